// Round 20
// baseline (663.008 us; speedup 1.0000x reference)
//
#include <hip/hip_runtime.h>
#include <hip/hip_bf16.h>

#define BB 4096
#define SZ 32
#define DD 10000
#define DPAD 10240
#define NMOD 64
#define NROWS_M 128   // Mh(64) + Ml(64)
#define KSPLIT 4
#define KSEG 2560     // DPAD / KSPLIT
#define NWORDS 160    // DPAD/64 packed words per row
#define STEPS 40      // KSEG/64

// ws layout (bytes)
#define WS_BK_OFF     0u                 // 160*128*64*2 = 2.62 MB
#define WS_CPK_OFF    3145728u           // 160*64*8 = 80 KB
#define WS_PACK_OFF   4194304u           // 160*4096*8 = 5.24 MB
#define WS_CPART_OFF  10485760u          // 4*4096*128*4 = 8.39 MB (end 18.9 MB)

typedef __attribute__((ext_vector_type(4))) float f32x4;
typedef __attribute__((ext_vector_type(8))) short short8;

static __device__ __forceinline__ ushort f2bf(float f) {
    unsigned u = __builtin_bit_cast(unsigned, f);
    unsigned r = (u + 0x7fffu + ((u >> 16) & 1u)) >> 16;   // RNE
    return (ushort)r;
}

// exact sign pipeline: 1 iff cosf(t+bk)*sinf(t) > 0, else 0 (incl t==0 -> -1)
static __device__ __forceinline__ int sign_pm(float t, float bk) {
    if (t == 0.0f) return 0;
    const double INV_PI_D = 0.31830988618379067153776752674503;
    float v = t + bk;
    long long n1 = (long long)floor((double)t * INV_PI_D);
    long long n2 = (long long)floor(fma((double)v, INV_PI_D, 0.5));
    return (int)(((n1 + n2) & 1LL) ^ 1LL);
}

// fast f32 parity with conservative guard band; falls back to exact f64 path
// when within EPS of a floor boundary (provably identical result otherwise:
// f32 computation error <= ~1.5e-6 << EPS).
static __device__ __forceinline__ int sign_fast(float t, float bk) {
    const float INV_PI_F = 0.31830988618379067f;
    const float EPS = 2e-5f;
    float v = t + bk;
    float u1 = t * INV_PI_F;
    float f1 = floorf(u1);
    float d1 = u1 - f1;
    float u2 = fmaf(v, INV_PI_F, 0.5f);
    float f2 = floorf(u2);
    float d2 = u2 - f2;
    bool risky = (t == 0.0f) | (d1 < EPS) | (d1 > 1.f - EPS) |
                 (d2 < EPS) | (d2 > 1.f - EPS);
    if (__builtin_expect(risky, 0)) return sign_pm(t, bk);
    int par = (int)f1 + (int)f2;
    return (par & 1) ^ 1;
}

// expand 8 packed bits (bit=1 -> +1.0bf16, 0 -> -1.0bf16) into short8
static __device__ __forceinline__ short8 expand8(unsigned b) {
    unsigned nb = ~b;
    unsigned r0 = 0x3F803F80u | ((nb & 1u) << 15) | ((nb & 2u) << 30);
    unsigned r1 = 0x3F803F80u | (((nb >> 2) & 1u) << 15) | (((nb >> 2) & 2u) << 30);
    unsigned r2 = 0x3F803F80u | (((nb >> 4) & 1u) << 15) | (((nb >> 4) & 2u) << 30);
    unsigned r3 = 0x3F803F80u | (((nb >> 6) & 1u) << 15) | (((nb >> 6) & 2u) << 30);
    uint4 u = make_uint4(r0, r1, r2, r3);
    return __builtin_bit_cast(short8, u);
}

// ---------------- K0: build Bk [160][128][64] bf16 (Mh, Ml) ---------------
__global__ __launch_bounds__(256) void k0_build_B(
        const float* __restrict__ M, ushort* __restrict__ Bk) {
    int k = blockIdx.x * 256 + threadIdx.x;   // 0..10239
    int row = blockIdx.y;                      // 0..127
    ushort u = 0;
    if (k < DD) {
        float m = M[(size_t)(row & 63) * DD + k];
        ushort mh = f2bf(m);
        if (row < 64) {
            u = mh;
        } else {
            float mhf = __builtin_bit_cast(float, (unsigned)mh << 16);
            u = f2bf(m - mhf);
        }
    }
    int step = k >> 6, kk = k & 63;
    Bk[((size_t)step * NROWS_M + row) * 64 + kk] = u;
}

// ---------------- K0b: pack cluster signs -> cpackT [160][64] u64 ---------
__global__ __launch_bounds__(256) void k0b_pack_c(
        const float* __restrict__ cluster, unsigned long long* __restrict__ cpackT) {
    const int tid = threadIdx.x;
    const int lane = tid & 63;
    const int wv = __builtin_amdgcn_readfirstlane(tid >> 6);
    const int w = blockIdx.x * 4 + wv;        // 0..159
    const int kb = w * 64;
    unsigned long long myw = 0;
    for (int m = 0; m < 64; ++m) {
        int k = kb + lane;
        int bit = (k < DD) ? (cluster[(size_t)m * DD + k] > 0.f ? 1 : 0) : 0;
        unsigned long long bal = __ballot(bit);
        if (lane == m) myw = bal;
    }
    cpackT[(size_t)w * 64 + lane] = myw;
}

// ---------------- K1: encode (T_G ordering), 2 cols/thread, wave skew -----
// x rows wave-uniform -> SGPR s_load double-buffer. Per row: 64 FMA + 2
// fast signs (~210 cyc) covers s_load latency; wave row-skew breaks the
// lockstep convoy so stalls interleave across waves.
__global__ __launch_bounds__(256, 4) void k1_enc(
        const float* __restrict__ x, const float* __restrict__ W,
        const float* __restrict__ bias, float* __restrict__ enc_out,
        unsigned long long* __restrict__ packedT) {
    const int tid = threadIdx.x;
    const int lane = tid & 63;
    const int wv = tid >> 6;
    const int i0 = blockIdx.y * 64;

    const int kA = blockIdx.x * 512 + tid;
    const int kB = kA + 256;
    const bool vA = (kA < DD), vB = (kB < DD);
    const int kwA = vA ? kA : 0, kwB = vB ? kB : 0;
    const int wordA = blockIdx.x * 8 + wv;
    const int wordB = wordA + 4;

    float4 a0, a1, a2, a3, a4, a5, a6, a7;
    float4 b0, b1, b2, b3, b4, b5, b6, b7;
    {
        const float* wpA = W + (size_t)kwA * SZ;
        asm volatile(
            "global_load_dwordx4 %0, %8, off\n\t"
            "global_load_dwordx4 %1, %8, off offset:16\n\t"
            "global_load_dwordx4 %2, %8, off offset:32\n\t"
            "global_load_dwordx4 %3, %8, off offset:48\n\t"
            "global_load_dwordx4 %4, %8, off offset:64\n\t"
            "global_load_dwordx4 %5, %8, off offset:80\n\t"
            "global_load_dwordx4 %6, %8, off offset:96\n\t"
            "global_load_dwordx4 %7, %8, off offset:112\n\t"
            "s_waitcnt vmcnt(0)"
            : "=&v"(a0), "=&v"(a1), "=&v"(a2), "=&v"(a3),
              "=&v"(a4), "=&v"(a5), "=&v"(a6), "=&v"(a7)
            : "v"(wpA));
        const float* wpB = W + (size_t)kwB * SZ;
        asm volatile(
            "global_load_dwordx4 %0, %8, off\n\t"
            "global_load_dwordx4 %1, %8, off offset:16\n\t"
            "global_load_dwordx4 %2, %8, off offset:32\n\t"
            "global_load_dwordx4 %3, %8, off offset:48\n\t"
            "global_load_dwordx4 %4, %8, off offset:64\n\t"
            "global_load_dwordx4 %5, %8, off offset:80\n\t"
            "global_load_dwordx4 %6, %8, off offset:96\n\t"
            "global_load_dwordx4 %7, %8, off offset:112\n\t"
            "s_waitcnt vmcnt(0)"
            : "=&v"(b0), "=&v"(b1), "=&v"(b2), "=&v"(b3),
              "=&v"(b4), "=&v"(b5), "=&v"(b6), "=&v"(b7)
            : "v"(wpB));
    }
    const float bkA = bias[kwA];
    const float bkB = bias[kwB];

    const float4* xb4 = reinterpret_cast<const float4*>(x + (size_t)i0 * SZ);
    const int rs = ((wv + blockIdx.x) & 3) * 16;   // wave/block row skew

    float4 xa[8], xb[8];
    #pragma unroll
    for (int q = 0; q < 8; ++q) xa[q] = xb4[rs * 8 + q];

    auto dorow = [&](int i, const float4* xr) {
        float gA0 = 0.f, gA1 = 0.f, gA2 = 0.f, gA3 = 0.f;
        float gB0 = 0.f, gB1 = 0.f, gB2 = 0.f, gB3 = 0.f;
        #pragma unroll
        for (int q = 0; q < 8; ++q) {
            const float4 wqA = (q == 0) ? a0 : (q == 1) ? a1 : (q == 2) ? a2 :
                               (q == 3) ? a3 : (q == 4) ? a4 : (q == 5) ? a5 :
                               (q == 6) ? a6 : a7;
            const float4 wqB = (q == 0) ? b0 : (q == 1) ? b1 : (q == 2) ? b2 :
                               (q == 3) ? b3 : (q == 4) ? b4 : (q == 5) ? b5 :
                               (q == 6) ? b6 : b7;
            float4 xc = xr[q];
            gA0 = fmaf(wqA.x, xc.x, gA0);
            gA1 = fmaf(wqA.y, xc.y, gA1);
            gA2 = fmaf(wqA.z, xc.z, gA2);
            gA3 = fmaf(wqA.w, xc.w, gA3);
            gB0 = fmaf(wqB.x, xc.x, gB0);
            gB1 = fmaf(wqB.y, xc.y, gB1);
            gB2 = fmaf(wqB.z, xc.z, gB2);
            gB3 = fmaf(wqB.w, xc.w, gB3);
        }
        float tA = (gA0 + gA1) + (gA2 + gA3);
        float tB = (gB0 + gB1) + (gB2 + gB3);
        int eA = vA ? sign_fast(tA, bkA) : 0;
        int eB = vB ? sign_fast(tB, bkB) : 0;
        unsigned long long balA = __ballot(eA);
        unsigned long long balB = __ballot(eB);
        if (lane == 0) {
            packedT[(size_t)wordA * BB + (i0 + i)] = balA;
            packedT[(size_t)wordB * BB + (i0 + i)] = balB;
        }
        if (vA) enc_out[(size_t)(i0 + i) * DD + kA] = eA ? 1.f : -1.f;
        if (vB) enc_out[(size_t)(i0 + i) * DD + kB] = eB ? 1.f : -1.f;
    };

    for (int ii = 0; ii < 64; ii += 2) {
        const int ia = (rs + ii) & 63;
        const int ib = (rs + ii + 1) & 63;
        #pragma unroll
        for (int q = 0; q < 8; ++q) xb[q] = xb4[ib * 8 + q];
        dorow(ia, xa);
        if (ii + 2 < 64) {
            const int ic = (rs + ii + 2) & 63;
            #pragma unroll
            for (int q = 0; q < 8; ++q) xa[q] = xb4[ic * 8 + q];
        }
        dorow(ib, xb);
    }
}

// ---------------- K2: fragment-direct MFMA GEMM, M-part only --------------
// grid (64 row-groups, 4 segs), 256 thr = 4 waves = 4 col-groups of 32.
__global__ __launch_bounds__(256, 2) void k2_gemm(
        const unsigned long long* __restrict__ packedT,  // [160][4096]
        const ushort* __restrict__ Bk,                   // [160][128][64]
        float* __restrict__ Cpart) {
    const int tid = threadIdx.x;
    const int wid = tid >> 6;       // col-group 0..3
    const int lane = tid & 63;
    const int fr = lane & 15;
    const int fg = lane >> 4;

    const int row0 = blockIdx.x * 64;
    const int seg = blockIdx.y;
    const int wcol = wid * 32;

    const unsigned long long* pA = packedT + (size_t)(seg * STEPS) * BB + row0 + fr;
    const ushort* pB = Bk + ((size_t)(seg * STEPS) * NROWS_M + wcol + fr) * 64 + fg * 8;

    f32x4 acc[4][2] = {};
    unsigned long long aw0[4], aw1[4];
    uint4 b0[2][2], b1[2][2];

#define LOADA(dst, s)                                         \
    _Pragma("unroll")                                         \
    for (int mt = 0; mt < 4; ++mt)                            \
        dst[mt] = pA[(size_t)(s) * BB + mt * 16];

#define LOADB(dst, s)                                         \
    _Pragma("unroll")                                         \
    for (int n = 0; n < 2; ++n) {                             \
        const ushort* p = pB + ((size_t)(s) * NROWS_M + n * 16) * 64; \
        dst[n][0] = *reinterpret_cast<const uint4*>(p);       \
        dst[n][1] = *reinterpret_cast<const uint4*>(p + 32);  \
    }

#define COMPUTE(aw, bf)                                       \
    _Pragma("unroll")                                         \
    for (int mt = 0; mt < 4; ++mt) {                          \
        unsigned lo = (unsigned)aw[mt];                       \
        unsigned hi = (unsigned)(aw[mt] >> 32);               \
        short8 af0 = expand8((lo >> (fg * 8)) & 0xffu);       \
        short8 af1 = expand8((hi >> (fg * 8)) & 0xffu);       \
        _Pragma("unroll")                                     \
        for (int n = 0; n < 2; ++n) {                         \
            acc[mt][n] = __builtin_amdgcn_mfma_f32_16x16x32_bf16( \
                af0, __builtin_bit_cast(short8, bf[n][0]), acc[mt][n], 0, 0, 0); \
            acc[mt][n] = __builtin_amdgcn_mfma_f32_16x16x32_bf16( \
                af1, __builtin_bit_cast(short8, bf[n][1]), acc[mt][n], 0, 0, 0); \
        }                                                     \
    }

    LOADA(aw0, 0)
    LOADB(b0, 0)

    for (int s = 0; s < STEPS; s += 2) {
        LOADA(aw1, s + 1)
        LOADB(b1, s + 1)
        COMPUTE(aw0, b0)
        if (s + 2 < STEPS) {
            LOADA(aw0, s + 2)
            LOADB(b0, s + 2)
        }
        COMPUTE(aw1, b1)
    }

    #pragma unroll
    for (int mt = 0; mt < 4; ++mt)
        #pragma unroll
        for (int n = 0; n < 2; ++n)
            #pragma unroll
            for (int r = 0; r < 4; ++r) {
                int grow = row0 + mt * 16 + fg * 4 + r;
                int col = wcol + n * 16 + fr;
                Cpart[((size_t)seg * BB + grow) * NROWS_M + col] = acc[mt][n][r];
            }
#undef LOADA
#undef LOADB
#undef COMPUTE
}

// ---------------- K3: popcount-sim + reduce + softmax + combine -----------
__global__ __launch_bounds__(256) void k3_final(
        const unsigned long long* __restrict__ packedT,
        const unsigned long long* __restrict__ cpackT,
        const float* __restrict__ Cpart, float* __restrict__ res) {
    const int tid = threadIdx.x;
    const int lane = tid & 63;                 // model index
    const int wv = __builtin_amdgcn_readfirstlane(tid >> 6);
    const int row = blockIdx.x * 4 + wv;

    // sim via XOR+popcount (pad bits are 0 on both sides -> cancel)
    int mis = 0;
    const unsigned long long* ap = packedT + row;
    const unsigned long long* cp = cpackT + lane;
    for (int w = 0; w < NWORDS; ++w) {
        unsigned long long a = ap[(size_t)w * BB];     // wave-uniform
        unsigned long long c = cp[(size_t)w * 64];
        mis += __popcll(a ^ c);
    }
    float sim = (float)(DD - 2 * mis) * 1e-4f;

    float mh = 0.f, ml = 0.f;
    #pragma unroll
    for (int seg = 0; seg < KSPLIT; ++seg) {
        const float* base = Cpart + ((size_t)seg * BB + row) * NROWS_M;
        mh += base[lane];
        ml += base[64 + lane];
    }
    float mr = mh + ml;

    float mx = sim;
    #pragma unroll
    for (int o = 32; o; o >>= 1) mx = fmaxf(mx, __shfl_xor(mx, o, 64));
    float e = expf(sim - mx);
    float num = e * mr;
    float Z = e;
    #pragma unroll
    for (int o = 32; o; o >>= 1) {
        Z += __shfl_xor(Z, o, 64);
        num += __shfl_xor(num, o, 64);
    }
    if (lane == 0) res[row] = num / Z;
}

extern "C" void kernel_launch(void* const* d_in, const int* in_sizes, int n_in,
                              void* d_out, int out_size, void* d_ws, size_t ws_size,
                              hipStream_t stream) {
    const float* x = (const float*)d_in[0];
    const float* W = (const float*)d_in[1];
    const float* bias = (const float*)d_in[2];
    const float* M = (const float*)d_in[3];
    const float* cluster = (const float*)d_in[4];

    float* res = (float*)d_out;            // [4096]
    float* enc = (float*)d_out + BB;       // [4096][10000]

    ushort* Bk = (ushort*)((char*)d_ws + WS_BK_OFF);
    unsigned long long* cpackT = (unsigned long long*)((char*)d_ws + WS_CPK_OFF);
    unsigned long long* packedT = (unsigned long long*)((char*)d_ws + WS_PACK_OFF);
    float* Cpart = (float*)((char*)d_ws + WS_CPART_OFF);

    k0_build_B<<<dim3(40, NROWS_M), 256, 0, stream>>>(M, Bk);
    k0b_pack_c<<<40, 256, 0, stream>>>(cluster, cpackT);
    k1_enc<<<dim3(20, 64), 256, 0, stream>>>(x, W, bias, enc, packedT);
    k2_gemm<<<dim3(64, KSPLIT), 256, 0, stream>>>(packedT, Bk, Cpart);
    k3_final<<<BB / 4, 256, 0, stream>>>(packedT, cpackT, Cpart, res);
}

// Round 21
// 161.200 us; speedup vs baseline: 4.1129x; 4.1129x over previous
//
#include <hip/hip_runtime.h>
#include <hip/hip_bf16.h>

#define BB 4096
#define SZ 32
#define DD 10000
#define DPAD 10240
#define NMOD 64
#define NROWS_M 128   // Mh(64) + Ml(64)
#define KSPLIT 4
#define KSEG 2560     // DPAD / KSPLIT
#define NWORDS 160    // DPAD/64 packed words per row
#define STEPS 40      // KSEG/64

// ws layout (bytes)
#define WS_BK_OFF     0u                 // 160*128*64*2 = 2.62 MB
#define WS_CPK_OFF    3145728u           // 160*64*8 = 80 KB
#define WS_PACK_OFF   4194304u           // 160*4096*8 = 5.24 MB
#define WS_CPART_OFF  10485760u          // 4*4096*128*4 = 8.39 MB (end 18.9 MB)

typedef __attribute__((ext_vector_type(4))) float f32x4;
typedef __attribute__((ext_vector_type(8))) short short8;

static __device__ __forceinline__ ushort f2bf(float f) {
    unsigned u = __builtin_bit_cast(unsigned, f);
    unsigned r = (u + 0x7fffu + ((u >> 16) & 1u)) >> 16;   // RNE
    return (ushort)r;
}

// exact sign pipeline: 1 iff cosf(t+bk)*sinf(t) > 0, else 0 (incl t==0 -> -1)
static __device__ __forceinline__ int sign_pm(float t, float bk) {
    if (t == 0.0f) return 0;
    const double INV_PI_D = 0.31830988618379067153776752674503;
    float v = t + bk;
    long long n1 = (long long)floor((double)t * INV_PI_D);
    long long n2 = (long long)floor(fma((double)v, INV_PI_D, 0.5));
    return (int)(((n1 + n2) & 1LL) ^ 1LL);
}

// fast f32 parity with conservative guard band; exact-f64 fallback near
// boundaries (f32 path error <= ~1.5e-6 << EPS). Validated round 20.
static __device__ __forceinline__ int sign_fast(float t, float bk) {
    const float INV_PI_F = 0.31830988618379067f;
    const float EPS = 2e-5f;
    float v = t + bk;
    float u1 = t * INV_PI_F;
    float f1 = floorf(u1);
    float d1 = u1 - f1;
    float u2 = fmaf(v, INV_PI_F, 0.5f);
    float f2 = floorf(u2);
    float d2 = u2 - f2;
    bool risky = (t == 0.0f) | (d1 < EPS) | (d1 > 1.f - EPS) |
                 (d2 < EPS) | (d2 > 1.f - EPS);
    if (__builtin_expect(risky, 0)) return sign_pm(t, bk);
    int par = (int)f1 + (int)f2;
    return (par & 1) ^ 1;
}

// expand 8 packed bits (bit=1 -> +1.0bf16, 0 -> -1.0bf16) into short8
static __device__ __forceinline__ short8 expand8(unsigned b) {
    unsigned nb = ~b;
    unsigned r0 = 0x3F803F80u | ((nb & 1u) << 15) | ((nb & 2u) << 30);
    unsigned r1 = 0x3F803F80u | (((nb >> 2) & 1u) << 15) | (((nb >> 2) & 2u) << 30);
    unsigned r2 = 0x3F803F80u | (((nb >> 4) & 1u) << 15) | (((nb >> 4) & 2u) << 30);
    unsigned r3 = 0x3F803F80u | (((nb >> 6) & 1u) << 15) | (((nb >> 6) & 2u) << 30);
    uint4 u = make_uint4(r0, r1, r2, r3);
    return __builtin_bit_cast(short8, u);
}

// ---------------- K0: build Bk [160][128][64] bf16 (Mh, Ml) ---------------
__global__ __launch_bounds__(256) void k0_build_B(
        const float* __restrict__ M, ushort* __restrict__ Bk) {
    int k = blockIdx.x * 256 + threadIdx.x;   // 0..10239
    int row = blockIdx.y;                      // 0..127
    ushort u = 0;
    if (k < DD) {
        float m = M[(size_t)(row & 63) * DD + k];
        ushort mh = f2bf(m);
        if (row < 64) {
            u = mh;
        } else {
            float mhf = __builtin_bit_cast(float, (unsigned)mh << 16);
            u = f2bf(m - mhf);
        }
    }
    int step = k >> 6, kk = k & 63;
    Bk[((size_t)step * NROWS_M + row) * 64 + kk] = u;
}

// ---------------- K0b: pack cluster signs -> cpackT [160][64] u64 ---------
__global__ __launch_bounds__(256) void k0b_pack_c(
        const float* __restrict__ cluster, unsigned long long* __restrict__ cpackT) {
    const int tid = threadIdx.x;
    const int lane = tid & 63;
    const int wv = __builtin_amdgcn_readfirstlane(tid >> 6);
    const int w = blockIdx.x * 4 + wv;        // 0..159
    const int kb = w * 64;
    unsigned long long myw = 0;
    for (int m = 0; m < 64; ++m) {
        int k = kb + lane;
        int bit = (k < DD) ? (cluster[(size_t)m * DD + k] > 0.f ? 1 : 0) : 0;
        unsigned long long bal = __ballot(bit);
        if (lane == m) myw = bal;
    }
    cpackT[(size_t)w * 64 + lane] = myw;
}

// ---------------- K1: encode (T_G ordering), 2 cols/thread ----------------
// x rows wave-uniform (plain loop index -> SGPR s_load double-buffer);
// W rows asm-pinned in 64 VGPRs; per row 64 FMA + 2 fast signs covers
// the s_load latency. NO row skew (keeps x provably uniform).
__global__ __launch_bounds__(256, 3) void k1_enc(
        const float* __restrict__ x, const float* __restrict__ W,
        const float* __restrict__ bias, float* __restrict__ enc_out,
        unsigned long long* __restrict__ packedT) {
    const int tid = threadIdx.x;
    const int lane = tid & 63;
    const int wv = tid >> 6;
    const int i0 = blockIdx.y * 64;

    const int kA = blockIdx.x * 512 + tid;
    const int kB = kA + 256;
    const bool vA = (kA < DD), vB = (kB < DD);
    const int kwA = vA ? kA : 0, kwB = vB ? kB : 0;
    const int wordA = blockIdx.x * 8 + wv;
    const int wordB = wordA + 4;

    float4 a0, a1, a2, a3, a4, a5, a6, a7;
    float4 b0, b1, b2, b3, b4, b5, b6, b7;
    {
        const float* wpA = W + (size_t)kwA * SZ;
        asm volatile(
            "global_load_dwordx4 %0, %8, off\n\t"
            "global_load_dwordx4 %1, %8, off offset:16\n\t"
            "global_load_dwordx4 %2, %8, off offset:32\n\t"
            "global_load_dwordx4 %3, %8, off offset:48\n\t"
            "global_load_dwordx4 %4, %8, off offset:64\n\t"
            "global_load_dwordx4 %5, %8, off offset:80\n\t"
            "global_load_dwordx4 %6, %8, off offset:96\n\t"
            "global_load_dwordx4 %7, %8, off offset:112\n\t"
            "s_waitcnt vmcnt(0)"
            : "=&v"(a0), "=&v"(a1), "=&v"(a2), "=&v"(a3),
              "=&v"(a4), "=&v"(a5), "=&v"(a6), "=&v"(a7)
            : "v"(wpA));
        const float* wpB = W + (size_t)kwB * SZ;
        asm volatile(
            "global_load_dwordx4 %0, %8, off\n\t"
            "global_load_dwordx4 %1, %8, off offset:16\n\t"
            "global_load_dwordx4 %2, %8, off offset:32\n\t"
            "global_load_dwordx4 %3, %8, off offset:48\n\t"
            "global_load_dwordx4 %4, %8, off offset:64\n\t"
            "global_load_dwordx4 %5, %8, off offset:80\n\t"
            "global_load_dwordx4 %6, %8, off offset:96\n\t"
            "global_load_dwordx4 %7, %8, off offset:112\n\t"
            "s_waitcnt vmcnt(0)"
            : "=&v"(b0), "=&v"(b1), "=&v"(b2), "=&v"(b3),
              "=&v"(b4), "=&v"(b5), "=&v"(b6), "=&v"(b7)
            : "v"(wpB));
    }
    const float bkA = bias[kwA];
    const float bkB = bias[kwB];

    const float4* xb4 = reinterpret_cast<const float4*>(x + (size_t)i0 * SZ);

    float4 xa[8], xb[8];
    #pragma unroll
    for (int q = 0; q < 8; ++q) xa[q] = xb4[q];     // row 0

    auto dorow = [&](int i, const float4* xr) {
        float gA0 = 0.f, gA1 = 0.f, gA2 = 0.f, gA3 = 0.f;
        float gB0 = 0.f, gB1 = 0.f, gB2 = 0.f, gB3 = 0.f;
        #pragma unroll
        for (int q = 0; q < 8; ++q) {
            const float4 wqA = (q == 0) ? a0 : (q == 1) ? a1 : (q == 2) ? a2 :
                               (q == 3) ? a3 : (q == 4) ? a4 : (q == 5) ? a5 :
                               (q == 6) ? a6 : a7;
            const float4 wqB = (q == 0) ? b0 : (q == 1) ? b1 : (q == 2) ? b2 :
                               (q == 3) ? b3 : (q == 4) ? b4 : (q == 5) ? b5 :
                               (q == 6) ? b6 : b7;
            float4 xc = xr[q];
            gA0 = fmaf(wqA.x, xc.x, gA0);
            gA1 = fmaf(wqA.y, xc.y, gA1);
            gA2 = fmaf(wqA.z, xc.z, gA2);
            gA3 = fmaf(wqA.w, xc.w, gA3);
            gB0 = fmaf(wqB.x, xc.x, gB0);
            gB1 = fmaf(wqB.y, xc.y, gB1);
            gB2 = fmaf(wqB.z, xc.z, gB2);
            gB3 = fmaf(wqB.w, xc.w, gB3);
        }
        float tA = (gA0 + gA1) + (gA2 + gA3);
        float tB = (gB0 + gB1) + (gB2 + gB3);
        int eA = vA ? sign_fast(tA, bkA) : 0;
        int eB = vB ? sign_fast(tB, bkB) : 0;
        unsigned long long balA = __ballot(eA);
        unsigned long long balB = __ballot(eB);
        if (lane == 0) {
            packedT[(size_t)wordA * BB + (i0 + i)] = balA;
            packedT[(size_t)wordB * BB + (i0 + i)] = balB;
        }
        if (vA) enc_out[(size_t)(i0 + i) * DD + kA] = eA ? 1.f : -1.f;
        if (vB) enc_out[(size_t)(i0 + i) * DD + kB] = eB ? 1.f : -1.f;
    };

    for (int i = 0; i < 64; i += 2) {
        #pragma unroll
        for (int q = 0; q < 8; ++q) xb[q] = xb4[(i + 1) * 8 + q];
        dorow(i, xa);
        if (i + 2 < 64) {
            #pragma unroll
            for (int q = 0; q < 8; ++q) xa[q] = xb4[(i + 2) * 8 + q];
        }
        dorow(i + 1, xb);
    }
}

// ---------------- K2: fragment-direct MFMA GEMM, M-part only --------------
// grid (64 row-groups, 4 segs), 256 thr = 4 waves = 4 col-groups of 32.
__global__ __launch_bounds__(256, 2) void k2_gemm(
        const unsigned long long* __restrict__ packedT,  // [160][4096]
        const ushort* __restrict__ Bk,                   // [160][128][64]
        float* __restrict__ Cpart) {
    const int tid = threadIdx.x;
    const int wid = tid >> 6;       // col-group 0..3
    const int lane = tid & 63;
    const int fr = lane & 15;
    const int fg = lane >> 4;

    const int row0 = blockIdx.x * 64;
    const int seg = blockIdx.y;
    const int wcol = wid * 32;

    const unsigned long long* pA = packedT + (size_t)(seg * STEPS) * BB + row0 + fr;
    const ushort* pB = Bk + ((size_t)(seg * STEPS) * NROWS_M + wcol + fr) * 64 + fg * 8;

    f32x4 acc[4][2] = {};
    unsigned long long aw0[4], aw1[4];
    uint4 b0[2][2], b1[2][2];

#define LOADA(dst, s)                                         \
    _Pragma("unroll")                                         \
    for (int mt = 0; mt < 4; ++mt)                            \
        dst[mt] = pA[(size_t)(s) * BB + mt * 16];

#define LOADB(dst, s)                                         \
    _Pragma("unroll")                                         \
    for (int n = 0; n < 2; ++n) {                             \
        const ushort* p = pB + ((size_t)(s) * NROWS_M + n * 16) * 64; \
        dst[n][0] = *reinterpret_cast<const uint4*>(p);       \
        dst[n][1] = *reinterpret_cast<const uint4*>(p + 32);  \
    }

#define COMPUTE(aw, bf)                                       \
    _Pragma("unroll")                                         \
    for (int mt = 0; mt < 4; ++mt) {                          \
        unsigned lo = (unsigned)aw[mt];                       \
        unsigned hi = (unsigned)(aw[mt] >> 32);               \
        short8 af0 = expand8((lo >> (fg * 8)) & 0xffu);       \
        short8 af1 = expand8((hi >> (fg * 8)) & 0xffu);       \
        _Pragma("unroll")                                     \
        for (int n = 0; n < 2; ++n) {                         \
            acc[mt][n] = __builtin_amdgcn_mfma_f32_16x16x32_bf16( \
                af0, __builtin_bit_cast(short8, bf[n][0]), acc[mt][n], 0, 0, 0); \
            acc[mt][n] = __builtin_amdgcn_mfma_f32_16x16x32_bf16( \
                af1, __builtin_bit_cast(short8, bf[n][1]), acc[mt][n], 0, 0, 0); \
        }                                                     \
    }

    LOADA(aw0, 0)
    LOADB(b0, 0)

    for (int s = 0; s < STEPS; s += 2) {
        LOADA(aw1, s + 1)
        LOADB(b1, s + 1)
        COMPUTE(aw0, b0)
        if (s + 2 < STEPS) {
            LOADA(aw0, s + 2)
            LOADB(b0, s + 2)
        }
        COMPUTE(aw1, b1)
    }

    #pragma unroll
    for (int mt = 0; mt < 4; ++mt)
        #pragma unroll
        for (int n = 0; n < 2; ++n)
            #pragma unroll
            for (int r = 0; r < 4; ++r) {
                int grow = row0 + mt * 16 + fg * 4 + r;
                int col = wcol + n * 16 + fr;
                Cpart[((size_t)seg * BB + grow) * NROWS_M + col] = acc[mt][n][r];
            }
#undef LOADA
#undef LOADB
#undef COMPUTE
}

// ---------------- K3: popcount-sim + reduce + softmax + combine -----------
__global__ __launch_bounds__(256) void k3_final(
        const unsigned long long* __restrict__ packedT,
        const unsigned long long* __restrict__ cpackT,
        const float* __restrict__ Cpart, float* __restrict__ res) {
    const int tid = threadIdx.x;
    const int lane = tid & 63;                 // model index
    const int wv = __builtin_amdgcn_readfirstlane(tid >> 6);
    const int row = blockIdx.x * 4 + wv;

    // sim via XOR+popcount (pad bits are 0 on both sides -> cancel)
    int mis = 0;
    const unsigned long long* ap = packedT + row;
    const unsigned long long* cp = cpackT + lane;
    for (int w = 0; w < NWORDS; ++w) {
        unsigned long long a = ap[(size_t)w * BB];     // wave-uniform
        unsigned long long c = cp[(size_t)w * 64];
        mis += __popcll(a ^ c);
    }
    float sim = (float)(DD - 2 * mis) * 1e-4f;

    float mh = 0.f, ml = 0.f;
    #pragma unroll
    for (int seg = 0; seg < KSPLIT; ++seg) {
        const float* base = Cpart + ((size_t)seg * BB + row) * NROWS_M;
        mh += base[lane];
        ml += base[64 + lane];
    }
    float mr = mh + ml;

    float mx = sim;
    #pragma unroll
    for (int o = 32; o; o >>= 1) mx = fmaxf(mx, __shfl_xor(mx, o, 64));
    float e = expf(sim - mx);
    float num = e * mr;
    float Z = e;
    #pragma unroll
    for (int o = 32; o; o >>= 1) {
        Z += __shfl_xor(Z, o, 64);
        num += __shfl_xor(num, o, 64);
    }
    if (lane == 0) res[row] = num / Z;
}

extern "C" void kernel_launch(void* const* d_in, const int* in_sizes, int n_in,
                              void* d_out, int out_size, void* d_ws, size_t ws_size,
                              hipStream_t stream) {
    const float* x = (const float*)d_in[0];
    const float* W = (const float*)d_in[1];
    const float* bias = (const float*)d_in[2];
    const float* M = (const float*)d_in[3];
    const float* cluster = (const float*)d_in[4];

    float* res = (float*)d_out;            // [4096]
    float* enc = (float*)d_out + BB;       // [4096][10000]

    ushort* Bk = (ushort*)((char*)d_ws + WS_BK_OFF);
    unsigned long long* cpackT = (unsigned long long*)((char*)d_ws + WS_CPK_OFF);
    unsigned long long* packedT = (unsigned long long*)((char*)d_ws + WS_PACK_OFF);
    float* Cpart = (float*)((char*)d_ws + WS_CPART_OFF);

    k0_build_B<<<dim3(40, NROWS_M), 256, 0, stream>>>(M, Bk);
    k0b_pack_c<<<40, 256, 0, stream>>>(cluster, cpackT);
    k1_enc<<<dim3(20, 64), 256, 0, stream>>>(x, W, bias, enc, packedT);
    k2_gemm<<<dim3(64, KSPLIT), 256, 0, stream>>>(packedT, Bk, Cpart);
    k3_final<<<BB / 4, 256, 0, stream>>>(packedT, cpackT, Cpart, res);
}